// Round 11
// baseline (45.298 us; speedup 1.0000x reference)
//
#include <hip/hip_runtime.h>
#include <math.h>

#define BB 4
#define C 64
#define H 128
#define W 128
#define HW (H*W)
#define KC 576            // GEMM K dim: col = k*64 + c
#define XR 6              // x-window rows
#define XC 38             // x-window cols

typedef __attribute__((ext_vector_type(4))) float f32x4;
typedef __attribute__((ext_vector_type(8))) _Float16 f16x8;

static __device__ __forceinline__ f16x8 splat8(float f) {
  _Float16 h = (_Float16)f;
  f16x8 v = {h, h, h, h, h, h, h, h};
  return v;
}

// ---------------- kernel 1: transpose x,c to NHWC f16 + frag-major weight prep
__global__ __launch_bounds__(256) void xpose_prep_kernel(
    const float* __restrict__ x, const float* __restrict__ cin,
    const float* __restrict__ wd, const float* __restrict__ woff,
    _Float16* __restrict__ xt, _Float16* __restrict__ ct,
    _Float16* __restrict__ wtbf, _Float16* __restrict__ wotf) {
  __shared__ _Float16 lds16[32 * 72];
  int t = threadIdx.x;

  if (blockIdx.y == 1 && blockIdx.x < 144) {
    int i = blockIdx.x * 256 + t;          // 0..36863
    {  // wtbf: [kb*4+ot][lane][8] <- w_dcn  (A-frag-major, coalesced loads)
      int j = i & 7, ln = (i >> 3) & 63, fi = i >> 9;   // fi 0..71
      int ot = fi & 3, kb = fi >> 2;
      int o = ot * 16 + (ln & 15);
      int kcol = kb * 32 + (ln >> 4) * 8 + j;
      int k = kcol >> 6, cc = kcol & 63;
      wtbf[i] = (_Float16)wd[(o * C + cc) * 9 + k];
    }
    if (i < 32 * KC) {  // wotf: [kb*2+ot2][lane][8] <- w_off (rows>=27 -> 0)
      int j = i & 7, ln = (i >> 3) & 63, fi = i >> 9;   // fi 0..35
      int ot2 = fi & 1, kb = fi >> 1;
      int o = ot2 * 16 + (ln & 15);
      int kcol = kb * 32 + (ln >> 4) * 8 + j;
      int k = kcol >> 6, cc = kcol & 63;
      wotf[i] = (o < 27) ? (_Float16)woff[(o * C + cc) * 9 + k] : (_Float16)0.f;
    }
  }

  const float* src = blockIdx.y ? cin : x;
  _Float16* dst = blockIdx.y ? ct : xt;

  int P0 = blockIdx.x * 32;
  int b = P0 >> 14;
  int pp0 = P0 & (HW - 1);

  int p = t & 31;
  int cg = t >> 5;
  const float* xb = src + (size_t)b * C * HW + pp0 + p;
  f16x8 u;
#pragma unroll
  for (int j = 0; j < 8; ++j)
    u[j] = (_Float16)xb[(cg * 8 + j) * HW];
  *(f16x8*)(lds16 + p * 72 + ((cg ^ (p & 7)) << 3)) = u;

  __syncthreads();

  int q = t >> 3;
  int s = t & 7;
  f16x8 v = *(const f16x8*)(lds16 + q * 72 + ((s ^ (q & 7)) << 3));
  *(f16x8*)(dst + (size_t)(P0 + q) * 64 + s * 8) = v;
}

// ---------------- kernel 2: fused DCN; LDS = 6x38 x-window only (29184 B)
// block = 64 px (2 rows x 32 cols), 4 waves; wave owns 16 px end-to-end.
__global__ __launch_bounds__(256) void dcn_fused_kernel(
    const _Float16* __restrict__ xt, const _Float16* __restrict__ ct,
    const _Float16* __restrict__ wtbf, const _Float16* __restrict__ wotf,
    const float* __restrict__ boff, const float* __restrict__ bd,
    float* __restrict__ out) {
  __shared__ _Float16 win[XR * XC * 64];         // 29184 B
  float* offT = (float*)win;                     // [4][16][36] overlay, 9216 B

  int tid = threadIdx.x;
  int bid = blockIdx.x;
  int w0 = (bid & 3) * 32;
  int h0 = ((bid >> 2) & 63) * 2;
  int b  = bid >> 8;

  int lane = tid & 63;
  int wv = tid >> 6;
  int lr = lane & 15, lh = lane >> 4;
  int h   = h0 + (wv >> 1);                      // wave-uniform row
  int wpx = w0 + (wv & 1) * 16 + lr;             // lane's pixel col

  const _Float16* xtb = xt + (size_t)b * HW * 64;
  const _Float16* ctb = ct + (size_t)b * HW * 64;

  int rlo = min(max(h0 - 2, 0), H - XR);
  int clo = min(max(w0 - 3, 0), W - XC);

  // ======== GEMM1: off[32o][16px]; B direct from global ct (coalesced) ====
  f32x4 acc1a = {0.f, 0.f, 0.f, 0.f};
  f32x4 acc1b = {0.f, 0.f, 0.f, 0.f};
#pragma unroll 2
  for (int kb = 0; kb < 18; ++kb) {
    int t9 = kb >> 1;
    int cg = (kb & 1) * 4 + lh;
    int ty = h + t9 / 3 - 1;
    int tx = wpx + t9 % 3 - 1;
    bool okv = (ty >= 0) && (ty < H) && (tx >= 0) && (tx < W);
    int yc = min(max(ty, 0), H - 1), xc = min(max(tx, 0), W - 1);
    f16x8 bf = *(const f16x8*)(ctb + (size_t)(yc * W + xc) * 64 + cg * 8);
    if (!okv) bf = splat8(0.f);
    f16x8 a0 = *(const f16x8*)(wotf + ((size_t)(kb * 2 + 0) * 64 + lane) * 8);
    f16x8 a1 = *(const f16x8*)(wotf + ((size_t)(kb * 2 + 1) * 64 + lane) * 8);
    acc1a = __builtin_amdgcn_mfma_f32_16x16x32_f16(a0, bf, acc1a, 0, 0, 0);
    acc1b = __builtin_amdgcn_mfma_f32_16x16x32_f16(a1, bf, acc1b, 0, 0, 0);
  }

  // write offT[wv][pixel][o] = acc + bias  (C/D: col=lr->pixel, row=lh*4+r->o)
  {
    f32x4 v0, v1;
#pragma unroll
    for (int r = 0; r < 4; ++r) {
      int o0 = lh * 4 + r;
      int o1 = 16 + lh * 4 + r;
      v0[r] = acc1a[r] + boff[o0];
      v1[r] = acc1b[r] + ((o1 < 27) ? boff[o1] : 0.f);
    }
    *(f32x4*)(offT + ((size_t)wv * 16 + lr) * 36 + lh * 4) = v0;
    *(f32x4*)(offT + ((size_t)wv * 16 + lr) * 36 + 16 + lh * 4) = v1;
  }
  __syncthreads();

  // pull this pixel's 27 offset/mask values into registers
  f32x4 rv[7];
#pragma unroll
  for (int j = 0; j < 7; ++j)
    rv[j] = *(const f32x4*)(offT + ((size_t)wv * 16 + lr) * 36 + 4 * j);
  __syncthreads();              // all reads done; staging may overwrite

#define OFFV(i) (rv[(i) >> 2][(i) & 3])

  // ---- stage x-window (6 rows x 38 cols), coalesced full lines ----
#pragma unroll
  for (int sweep = 0; sweep < 8; ++sweep) {
    int cch = sweep * 256 + tid;                 // 16-B chunks, 1824 total
    if (cch < XR * XC * 8) {
      int row = cch / (XC * 8);
      int rem = cch - row * (XC * 8);
      int col = rem >> 3, part = rem & 7;
      int pix = cch >> 3;
      *(f16x8*)(win + (size_t)pix * 64 + ((part ^ (pix & 7)) << 3)) =
        *(const f16x8*)(xtb + ((size_t)(rlo + row) * W + clo + col) * 64 + part * 8);
    }
  }
  __syncthreads();

  // ---- sample + GEMM2 (k fully unrolled; offsets in registers) ----
  f32x4 acc[4];
#pragma unroll
  for (int i = 0; i < 4; ++i) acc[i] = (f32x4){0.f, 0.f, 0.f, 0.f};

#pragma unroll
  for (int k = 0; k < 9; ++k) {
    float dy = OFFV(2 * k);
    float dx = OFFV(2 * k + 1);
    float mv = OFFV(18 + k);
    float m = 1.0f / (1.0f + __expf(-mv));

    float py = (float)(h + k / 3 - 1) + dy;
    float px = (float)(wpx + k % 3 - 1) + dx;
    float y0f = floorf(py), x0f = floorf(px);
    int y0 = (int)y0f, x0 = (int)x0f;
    float wy1 = py - y0f, wx1 = px - x0f;
    float wy0 = 1.0f - wy1, wx0 = 1.0f - wx1;

    bool y0v = (y0 >= 0) && (y0 < H);
    bool y1v = (y0 + 1 >= 0) && (y0 + 1 < H);
    bool x0v = (x0 >= 0) && (x0 < W);
    bool x1v = (x0 + 1 >= 0) && (x0 + 1 < W);
    int y0c = min(max(y0, 0), H - 1), y1c = min(max(y0 + 1, 0), H - 1);
    int x0c = min(max(x0, 0), W - 1), x1c = min(max(x0 + 1, 0), W - 1);

    float w00 = wy0 * wx0 * (float)(y0v && x0v) * m;
    float w01 = wy0 * wx1 * (float)(y0v && x1v) * m;
    float w10 = wy1 * wx0 * (float)(y1v && x0v) * m;
    float w11 = wy1 * wx1 * (float)(y1v && x1v) * m;

    int iy0 = y0c - rlo, iy1 = y1c - rlo;
    int ix0 = x0c - clo, ix1 = x1c - clo;
    bool inY0 = (unsigned)iy0 < XR, inY1 = (unsigned)iy1 < XR;
    bool inX0 = (unsigned)ix0 < XC, inX1 = (unsigned)ix1 < XC;
    bool in00 = inY0 && inX0, in01 = inY0 && inX1;
    bool in10 = inY1 && inX0, in11 = inY1 && inX1;
    int p00 = min(max(iy0, 0), XR - 1) * XC + min(max(ix0, 0), XC - 1);
    int p01 = min(max(iy0, 0), XR - 1) * XC + min(max(ix1, 0), XC - 1);
    int p10 = min(max(iy1, 0), XR - 1) * XC + min(max(ix0, 0), XC - 1);
    int p11 = min(max(iy1, 0), XR - 1) * XC + min(max(ix1, 0), XC - 1);

#pragma unroll
    for (int half = 0; half < 2; ++half) {
      int cg = half * 4 + lh;
      f16x8 c00 = *(const f16x8*)(win + (size_t)p00 * 64 + ((cg ^ (p00 & 7)) << 3));
      f16x8 c01 = *(const f16x8*)(win + (size_t)p01 * 64 + ((cg ^ (p01 & 7)) << 3));
      f16x8 c10 = *(const f16x8*)(win + (size_t)p10 * 64 + ((cg ^ (p10 & 7)) << 3));
      f16x8 c11 = *(const f16x8*)(win + (size_t)p11 * 64 + ((cg ^ (p11 & 7)) << 3));
      // rare fallback: offset pushed sample outside staged window (exec-masked)
      if (!in00) c00 = *(const f16x8*)(xtb + ((size_t)y0c * W + x0c) * 64 + cg * 8);
      if (!in01) c01 = *(const f16x8*)(xtb + ((size_t)y0c * W + x1c) * 64 + cg * 8);
      if (!in10) c10 = *(const f16x8*)(xtb + ((size_t)y1c * W + x0c) * 64 + cg * 8);
      if (!in11) c11 = *(const f16x8*)(xtb + ((size_t)y1c * W + x1c) * 64 + cg * 8);

      f16x8 s = c00 * splat8(w00);
      s += c01 * splat8(w01);
      s += c10 * splat8(w10);
      s += c11 * splat8(w11);          // this IS the B-fragment for kb

      int kb = 2 * k + half;
#pragma unroll
      for (int ot = 0; ot < 4; ++ot) {
        f16x8 a = *(const f16x8*)(wtbf + ((size_t)(kb * 4 + ot) * 64 + lane) * 8);
        acc[ot] = __builtin_amdgcn_mfma_f32_16x16x32_f16(a, s, acc[ot], 0, 0, 0);
      }
    }
  }

  // ---- epilogue ----
#pragma unroll
  for (int ot = 0; ot < 4; ++ot) {
#pragma unroll
    for (int r = 0; r < 4; ++r) {
      int o = ot * 16 + lh * 4 + r;
      size_t base = ((size_t)(b * C + o)) * HW + (size_t)h * W + w0 + (wv & 1) * 16 + lr;
      out[base] = acc[ot][r] + bd[o];
    }
  }
}

extern "C" void kernel_launch(void* const* d_in, const int* in_sizes, int n_in,
                              void* d_out, int out_size, void* d_ws, size_t ws_size,
                              hipStream_t stream) {
  const float* x    = (const float*)d_in[0];
  const float* c    = (const float*)d_in[1];
  const float* woff = (const float*)d_in[2];
  const float* boff = (const float*)d_in[3];
  const float* wdcn = (const float*)d_in[4];
  const float* bdcn = (const float*)d_in[5];
  float* out = (float*)d_out;

  _Float16* xt   = (_Float16*)d_ws;                   // 4,194,304 f16
  _Float16* ct   = xt + 4194304;                      // 4,194,304 f16
  _Float16* wtbf = ct + 4194304;                      // 36,864 f16
  _Float16* wotf = wtbf + 36864;                      // 18,432 f16

  int npix = BB * H * W;                              // 65536
  dim3 gx(npix / 32, 2);
  xpose_prep_kernel<<<gx, 256, 0, stream>>>(x, c, wdcn, woff, xt, ct, wtbf, wotf);
  dcn_fused_kernel<<<npix / 64, 256, 0, stream>>>(xt, ct, wtbf, wotf, boff, bdcn, out);
}

// Round 12
// 39.891 us; speedup vs baseline: 1.1355x; 1.1355x over previous
//
#include <hip/hip_runtime.h>
#include <math.h>

#define BB 4
#define C 64
#define H 128
#define W 128
#define HW (H*W)
#define KC 576            // GEMM K dim: col = k*64 + c
#define XR 6              // x-window rows
#define XC 38             // x-window cols
#define CR 4              // c-window rows
#define CCW 34            // c-window cols
#define OFFS 28           // offT per-pixel stride (f16)

typedef __attribute__((ext_vector_type(4))) float f32x4;
typedef __attribute__((ext_vector_type(4))) _Float16 f16x4;
typedef __attribute__((ext_vector_type(8))) _Float16 f16x8;

static __device__ __forceinline__ f16x8 splat8(float f) {
  _Float16 h = (_Float16)f;
  f16x8 v = {h, h, h, h, h, h, h, h};
  return v;
}

// ---------------- kernel 1: transpose x,c to NHWC f16 + frag-major weight prep
__global__ __launch_bounds__(256) void xpose_prep_kernel(
    const float* __restrict__ x, const float* __restrict__ cin,
    const float* __restrict__ wd, const float* __restrict__ woff,
    _Float16* __restrict__ xt, _Float16* __restrict__ ct,
    _Float16* __restrict__ wtbf, _Float16* __restrict__ wotf) {
  __shared__ _Float16 lds16[32 * 72];
  int t = threadIdx.x;

  if (blockIdx.y == 1 && blockIdx.x < 144) {
    int i = blockIdx.x * 256 + t;          // 0..36863
    {  // wtbf: [kb*4+ot][lane][8] <- w_dcn  (A-frag-major, coalesced loads)
      int j = i & 7, ln = (i >> 3) & 63, fi = i >> 9;   // fi 0..71
      int ot = fi & 3, kb = fi >> 2;
      int o = ot * 16 + (ln & 15);
      int kcol = kb * 32 + (ln >> 4) * 8 + j;
      int k = kcol >> 6, cc = kcol & 63;
      wtbf[i] = (_Float16)wd[(o * C + cc) * 9 + k];
    }
    if (i < 32 * KC) {  // wotf: [kb*2+ot2][lane][8] <- w_off (rows>=27 -> 0)
      int j = i & 7, ln = (i >> 3) & 63, fi = i >> 9;   // fi 0..35
      int ot2 = fi & 1, kb = fi >> 1;
      int o = ot2 * 16 + (ln & 15);
      int kcol = kb * 32 + (ln >> 4) * 8 + j;
      int k = kcol >> 6, cc = kcol & 63;
      wotf[i] = (o < 27) ? (_Float16)woff[(o * C + cc) * 9 + k] : (_Float16)0.f;
    }
  }

  const float* src = blockIdx.y ? cin : x;
  _Float16* dst = blockIdx.y ? ct : xt;

  int P0 = blockIdx.x * 32;
  int b = P0 >> 14;
  int pp0 = P0 & (HW - 1);

  int p = t & 31;
  int cg = t >> 5;
  const float* xb = src + (size_t)b * C * HW + pp0 + p;
  f16x8 u;
#pragma unroll
  for (int j = 0; j < 8; ++j)
    u[j] = (_Float16)xb[(cg * 8 + j) * HW];
  *(f16x8*)(lds16 + p * 72 + ((cg ^ (p & 7)) << 3)) = u;

  __syncthreads();

  int q = t >> 3;
  int s = t & 7;
  f16x8 v = *(const f16x8*)(lds16 + q * 72 + ((s ^ (q & 7)) << 3));
  *(f16x8*)(dst + (size_t)(P0 + q) * 64 + s * 8) = v;
}

// ---------------- kernel 2: fused DCN; LDS = 32768 B exactly -> 5 blocks/CU
// win[29184]: c-window(17408) then x-window(29184). offT[3584]: f16 offsets.
// block = 64 px (2 rows x 32 cols), 4 waves; wave owns 16 px end-to-end.
__global__ __launch_bounds__(256) void dcn_fused_kernel(
    const _Float16* __restrict__ xt, const _Float16* __restrict__ ct,
    const _Float16* __restrict__ wtbf, const _Float16* __restrict__ wotf,
    const float* __restrict__ boff, const float* __restrict__ bd,
    float* __restrict__ out) {
  __shared__ __align__(16) unsigned char smem[32768];
  _Float16* win  = (_Float16*)smem;                 // windows (overlaid)
  _Float16* offT = (_Float16*)(smem + 29184);       // [4][16][28] f16

  int tid = threadIdx.x;
  int bid = blockIdx.x;
  int w0 = (bid & 3) * 32;
  int h0 = ((bid >> 2) & 63) * 2;
  int b  = bid >> 8;

  int lane = tid & 63;
  int wv = tid >> 6;
  int lr = lane & 15, lh = lane >> 4;
  int h   = h0 + (wv >> 1);                      // wave-uniform row
  int wpx = w0 + (wv & 1) * 16 + lr;             // lane's pixel col

  const _Float16* xtb = xt + (size_t)b * HW * 64;
  const _Float16* ctb = ct + (size_t)b * HW * 64;

  int crlo = min(max(h0 - 1, 0), H - CR);
  int cclo = min(max(w0 - 1, 0), W - CCW);
  int rlo  = min(max(h0 - 2, 0), H - XR);
  int clo  = min(max(w0 - 3, 0), W - XC);

  // ---- stage c-window (4 x 34), coalesced full lines ----
#pragma unroll
  for (int sweep = 0; sweep < 5; ++sweep) {
    int cch = sweep * 256 + tid;                 // 16-B chunks, 1088 total
    if (cch < CR * CCW * 8) {
      int pixw = cch >> 3, part = cch & 7;
      int row = pixw / CCW, col = pixw - row * CCW;
      *(f16x8*)(win + (size_t)pixw * 64 + ((part ^ (pixw & 7)) << 3)) =
        *(const f16x8*)(ctb + ((size_t)(crlo + row) * W + cclo + col) * 64 + part * 8);
    }
  }
  __syncthreads();

  // ---- GEMM1: off[32o][16px]; B from c-window LDS, A frag-major ----
  f32x4 acc1a = {0.f, 0.f, 0.f, 0.f};
  f32x4 acc1b = {0.f, 0.f, 0.f, 0.f};
#pragma unroll 2
  for (int kb = 0; kb < 18; ++kb) {
    int t9 = kb >> 1;
    int cg = (kb & 1) * 4 + lh;
    int ty = h + t9 / 3 - 1;
    int tx = wpx + t9 % 3 - 1;
    bool okv = (ty >= 0) && (ty < H) && (tx >= 0) && (tx < W);
    int pixw = (min(max(ty, 0), H - 1) - crlo) * CCW
             + (min(max(tx, 0), W - 1) - cclo);
    f16x8 bf = *(const f16x8*)(win + (size_t)pixw * 64 + ((cg ^ (pixw & 7)) << 3));
    if (!okv) bf = splat8(0.f);
    f16x8 a0 = *(const f16x8*)(wotf + ((size_t)(kb * 2 + 0) * 64 + lane) * 8);
    f16x8 a1 = *(const f16x8*)(wotf + ((size_t)(kb * 2 + 1) * 64 + lane) * 8);
    acc1a = __builtin_amdgcn_mfma_f32_16x16x32_f16(a0, bf, acc1a, 0, 0, 0);
    acc1b = __builtin_amdgcn_mfma_f32_16x16x32_f16(a1, bf, acc1b, 0, 0, 0);
  }

  // offT[wv][pixel][o] = f16(acc + bias); same-wave produce/consume
  {
    f16x4 v0, v1;
#pragma unroll
    for (int r = 0; r < 4; ++r) {
      int o0 = lh * 4 + r;
      int o1 = 16 + lh * 4 + r;
      v0[r] = (_Float16)(acc1a[r] + boff[o0]);
      v1[r] = (_Float16)(acc1b[r] + ((o1 < 27) ? boff[o1] : 0.f));
    }
    _Float16* base = offT + ((size_t)wv * 16 + lr) * OFFS;
    *(f16x4*)(base + lh * 4) = v0;
    if (lh < 3) *(f16x4*)(base + 16 + lh * 4) = v1;
  }
  __syncthreads();   // all c-window reads done -> x-stage may overwrite win

  // ---- stage x-window (6 x 38) + pull offsets (disjoint LDS regions) ----
#pragma unroll
  for (int sweep = 0; sweep < 8; ++sweep) {
    int cch = sweep * 256 + tid;                 // 1824 chunks
    if (cch < XR * XC * 8) {
      int pixw = cch >> 3, part = cch & 7;
      int row = pixw / XC, col = pixw - row * XC;
      *(f16x8*)(win + (size_t)pixw * 64 + ((part ^ (pixw & 7)) << 3)) =
        *(const f16x8*)(xtb + ((size_t)(rlo + row) * W + clo + col) * 64 + part * 8);
    }
  }
  f16x4 rvh[7];
#pragma unroll
  for (int j = 0; j < 7; ++j)
    rvh[j] = *(const f16x4*)(offT + ((size_t)wv * 16 + lr) * OFFS + 4 * j);
  __syncthreads();

#define OFFV(i) ((float)rvh[(i) >> 2][(i) & 3])

  // ---- sample + GEMM2 (k fully unrolled; offsets static in registers) ----
  f32x4 acc[4];
#pragma unroll
  for (int i = 0; i < 4; ++i) acc[i] = (f32x4){0.f, 0.f, 0.f, 0.f};

#pragma unroll
  for (int k = 0; k < 9; ++k) {
    float dy = OFFV(2 * k);
    float dx = OFFV(2 * k + 1);
    float mv = OFFV(18 + k);
    float m = 1.0f / (1.0f + __expf(-mv));

    float py = (float)(h + k / 3 - 1) + dy;
    float px = (float)(wpx + k % 3 - 1) + dx;
    float y0f = floorf(py), x0f = floorf(px);
    int y0 = (int)y0f, x0 = (int)x0f;
    float wy1 = py - y0f, wx1 = px - x0f;
    float wy0 = 1.0f - wy1, wx0 = 1.0f - wx1;

    bool y0v = (y0 >= 0) && (y0 < H);
    bool y1v = (y0 + 1 >= 0) && (y0 + 1 < H);
    bool x0v = (x0 >= 0) && (x0 < W);
    bool x1v = (x0 + 1 >= 0) && (x0 + 1 < W);
    int y0c = min(max(y0, 0), H - 1), y1c = min(max(y0 + 1, 0), H - 1);
    int x0c = min(max(x0, 0), W - 1), x1c = min(max(x0 + 1, 0), W - 1);

    float w00 = wy0 * wx0 * (float)(y0v && x0v) * m;
    float w01 = wy0 * wx1 * (float)(y0v && x1v) * m;
    float w10 = wy1 * wx0 * (float)(y1v && x0v) * m;
    float w11 = wy1 * wx1 * (float)(y1v && x1v) * m;

    int iy0 = y0c - rlo, iy1 = y1c - rlo;
    int ix0 = x0c - clo, ix1 = x1c - clo;
    bool inY0 = (unsigned)iy0 < XR, inY1 = (unsigned)iy1 < XR;
    bool inX0 = (unsigned)ix0 < XC, inX1 = (unsigned)ix1 < XC;
    bool in00 = inY0 && inX0, in01 = inY0 && inX1;
    bool in10 = inY1 && inX0, in11 = inY1 && inX1;
    int p00 = min(max(iy0, 0), XR - 1) * XC + min(max(ix0, 0), XC - 1);
    int p01 = min(max(iy0, 0), XR - 1) * XC + min(max(ix1, 0), XC - 1);
    int p10 = min(max(iy1, 0), XR - 1) * XC + min(max(ix0, 0), XC - 1);
    int p11 = min(max(iy1, 0), XR - 1) * XC + min(max(ix1, 0), XC - 1);

#pragma unroll
    for (int half = 0; half < 2; ++half) {
      int cg = half * 4 + lh;
      f16x8 c00 = *(const f16x8*)(win + (size_t)p00 * 64 + ((cg ^ (p00 & 7)) << 3));
      f16x8 c01 = *(const f16x8*)(win + (size_t)p01 * 64 + ((cg ^ (p01 & 7)) << 3));
      f16x8 c10 = *(const f16x8*)(win + (size_t)p10 * 64 + ((cg ^ (p10 & 7)) << 3));
      f16x8 c11 = *(const f16x8*)(win + (size_t)p11 * 64 + ((cg ^ (p11 & 7)) << 3));
      // rare fallback: offset pushed sample outside staged window (exec-masked)
      if (!in00) c00 = *(const f16x8*)(xtb + ((size_t)y0c * W + x0c) * 64 + cg * 8);
      if (!in01) c01 = *(const f16x8*)(xtb + ((size_t)y0c * W + x1c) * 64 + cg * 8);
      if (!in10) c10 = *(const f16x8*)(xtb + ((size_t)y1c * W + x0c) * 64 + cg * 8);
      if (!in11) c11 = *(const f16x8*)(xtb + ((size_t)y1c * W + x1c) * 64 + cg * 8);

      f16x8 s = c00 * splat8(w00);
      s += c01 * splat8(w01);
      s += c10 * splat8(w10);
      s += c11 * splat8(w11);          // this IS the B-fragment for kb

      int kb = 2 * k + half;
#pragma unroll
      for (int ot = 0; ot < 4; ++ot) {
        f16x8 a = *(const f16x8*)(wtbf + ((size_t)(kb * 4 + ot) * 64 + lane) * 8);
        acc[ot] = __builtin_amdgcn_mfma_f32_16x16x32_f16(a, s, acc[ot], 0, 0, 0);
      }
    }
  }

  // ---- epilogue ----
#pragma unroll
  for (int ot = 0; ot < 4; ++ot) {
#pragma unroll
    for (int r = 0; r < 4; ++r) {
      int o = ot * 16 + lh * 4 + r;
      size_t base = ((size_t)(b * C + o)) * HW + (size_t)h * W + w0 + (wv & 1) * 16 + lr;
      out[base] = acc[ot][r] + bd[o];
    }
  }
}

extern "C" void kernel_launch(void* const* d_in, const int* in_sizes, int n_in,
                              void* d_out, int out_size, void* d_ws, size_t ws_size,
                              hipStream_t stream) {
  const float* x    = (const float*)d_in[0];
  const float* c    = (const float*)d_in[1];
  const float* woff = (const float*)d_in[2];
  const float* boff = (const float*)d_in[3];
  const float* wdcn = (const float*)d_in[4];
  const float* bdcn = (const float*)d_in[5];
  float* out = (float*)d_out;

  _Float16* xt   = (_Float16*)d_ws;                   // 4,194,304 f16
  _Float16* ct   = xt + 4194304;                      // 4,194,304 f16
  _Float16* wtbf = ct + 4194304;                      // 36,864 f16
  _Float16* wotf = wtbf + 36864;                      // 18,432 f16

  int npix = BB * H * W;                              // 65536
  dim3 gx(npix / 32, 2);
  xpose_prep_kernel<<<gx, 256, 0, stream>>>(x, c, wdcn, woff, xt, ct, wtbf, wotf);
  dcn_fused_kernel<<<npix / 64, 256, 0, stream>>>(xt, ct, wtbf, wotf, boff, bdcn, out);
}